// Round 4
// baseline (156.578 us; speedup 1.0000x reference)
//
#include <hip/hip_runtime.h>
#include <hip/hip_fp16.h>

#define N_NODES 50000
#define N_EDGES 800000
#define TOT_E   (N_EDGES + N_NODES)
#define NEG_SLOPE 0.2f
#define MB_SHIFT 8.0f   // fixed softmax shift: valid upper bound for e=as+ad (|e|<~3);
                        // softmax is shift-invariant so result is exact up to fp rounding.

#define SHIFT  6
#define NBUCK  ((N_NODES + 63) >> SHIFT)       // 782 buckets of 64 nodes
#define NBP    1024                             // padded scan width
#define CHUNK  4096                             // 208 binscatter blocks
#define EPT    (CHUNK / 256)                    // 16 edges per thread
#define NCHUNK ((TOT_E + CHUNK - 1) / CHUNK)
#define HPART  32                               // partial-histogram blocks
#define NGEMM1 ((N_NODES + 63) / 64)            // 782 GEMM1 blocks (BM=64)

// ---------- edge fetch (handles int32 or int64 edge_index; self-loops appended) ----------
__device__ __forceinline__ void get_edge(const void* edges, int flag64, long long i,
                                         int& src, int& dst) {
    if (i < N_EDGES) {
        if (flag64) {
            const long long* e = (const long long*)edges;
            src = (int)e[i];
            dst = (int)e[N_EDGES + i];
        } else {
            const int* e = (const int*)edges;
            src = e[i];
            dst = e[(long long)N_EDGES + i];
        }
    } else {
        src = dst = (int)(i - N_EDGES);
    }
}

__device__ __forceinline__ int get_dst(const void* edges, int flag64, long long i) {
    if (i < N_EDGES) {
        if (flag64) return (int)((const long long*)edges)[N_EDGES + i];
        return ((const int*)edges)[(long long)N_EDGES + i];
    }
    return (int)(i - N_EDGES);
}

// per-block edge-dtype detection: wave 0 checks first 64 int64 slots, one ballot.
// (int32 data reinterpreted as int64 is out of [0,N_NODES) unless every high word
// is 0 and low word valid -- same heuristic as the previous global k_init.)
__device__ __forceinline__ int detect64(const void* edges, int tid, int* sfl) {
    if (tid < 64) {
        long long v = ((const long long*)edges)[tid];
        unsigned long long ok = __ballot(v >= 0 && v < N_NODES);
        if (tid == 0) *sfl = (ok == ~0ull) ? 1 : 0;
    }
    __syncthreads();
    return *sfl;
}

// ---------- partial bucket histograms: HPART blocks, no global atomics, no pre-zero ----------
__global__ __launch_bounds__(256) void k_binhist(const void* edges, int* __restrict__ part) {
    __shared__ int h[NBUCK];
    __shared__ int sfl;
    const int tid = threadIdx.x;
    for (int i = tid; i < NBUCK; i += 256) h[i] = 0;
    const int fl = detect64(edges, tid, &sfl);   // includes __syncthreads()
    const long long per = (TOT_E + HPART - 1) / HPART;
    const long long i0 = (long long)blockIdx.x * per;
    const long long i1 = (i0 + per < TOT_E) ? (i0 + per) : TOT_E;
    for (long long i = i0 + tid; i < i1; i += 256)
        atomicAdd(&h[get_dst(edges, fl, i) >> SHIFT], 1);
    __syncthreads();
    int* dst = part + blockIdx.x * NBUCK;
    for (int i = tid; i < NBUCK; i += 256) dst[i] = h[i];
}

// ---------- single-block: reduce partials + scan -> boffs, gcur ----------
__global__ __launch_bounds__(256) void k_bscan(const int* __restrict__ part,
                                               int* __restrict__ boffs,
                                               int* __restrict__ gcur) {
    __shared__ int sc[NBP];
    __shared__ int orig[NBP];
    const int tid = threadIdx.x;
    for (int s = 0; s < 4; s++) {
        int i = tid + s * 256;
        int v = 0;
        if (i < NBUCK) {
#pragma unroll
            for (int r = 0; r < HPART; r++) v += part[r * NBUCK + i];
        }
        sc[i] = v;
        orig[i] = v;
    }
    __syncthreads();
    for (int off = 1; off < NBP; off <<= 1) {
        int t[4];
        for (int s = 0; s < 4; s++) {
            int a = tid + s * 256;
            t[s] = (a >= off) ? sc[a - off] : 0;
        }
        __syncthreads();
        for (int s = 0; s < 4; s++) sc[tid + s * 256] += t[s];
        __syncthreads();
    }
    for (int s = 0; s < 4; s++) {
        int i = tid + s * 256;
        if (i < NBUCK) {
            int e = sc[i] - orig[i];   // exclusive
            boffs[i] = e;
            gcur[i]  = e;
        }
    }
    if (tid == 0) boffs[NBUCK] = sc[NBUCK - 1];
}

// ---------- chunked binscatter: group chunk's edges by bucket in LDS, write runs ----------
__global__ __launch_bounds__(256) void k_binscatter(const void* edges,
                                                    int* gcur, unsigned int* staging) {
    __shared__ int sc[NBP];        // counts -> inclusive scan
    __shared__ int so[NBP];        // original counts
    __shared__ int sr[NBUCK];      // running cursor (phase 3)
    __shared__ int gb[NBUCK];      // global base per bucket
    __shared__ unsigned int buf[CHUNK];
    __shared__ int sfl;
    const int tid = threadIdx.x;
    const int c0 = blockIdx.x * CHUNK;
    const int nE = min(CHUNK, TOT_E - c0);
    unsigned int pk[EPT];

    for (int s = 0; s < 4; s++) sc[tid + s * 256] = 0;
    for (int i = tid; i < NBUCK; i += 256) sr[i] = 0;
    const int fl = detect64(edges, tid, &sfl);   // includes __syncthreads()
    // phase 1: read edges, pack, count
#pragma unroll
    for (int j = 0; j < EPT; j++) {
        int li = j * 256 + tid;
        pk[j] = 0u;
        if (li < nE) {
            int src, dst;
            get_edge(edges, fl, (long long)(c0 + li), src, dst);
            pk[j] = ((unsigned int)dst << 16) | (unsigned int)src;
            atomicAdd(&sc[dst >> SHIFT], 1);
        }
    }
    __syncthreads();
    for (int s = 0; s < 4; s++) { int i = tid + s * 256; so[i] = sc[i]; }
    __syncthreads();
    // phase 2: inclusive scan of sc
    for (int off = 1; off < NBP; off <<= 1) {
        int t[4];
        for (int s = 0; s < 4; s++) {
            int a = tid + s * 256;
            t[s] = (a >= off) ? sc[a - off] : 0;
        }
        __syncthreads();
        for (int s = 0; s < 4; s++) sc[tid + s * 256] += t[s];
        __syncthreads();
    }
    // reserve global ranges
    for (int b = tid; b < NBUCK; b += 256)
        if (so[b]) gb[b] = atomicAdd(&gcur[b], so[b]);
    __syncthreads();
    // phase 3: place packed edges bucket-grouped in LDS
#pragma unroll
    for (int j = 0; j < EPT; j++) {
        int li = j * 256 + tid;
        if (li < nE) {
            int b = pk[j] >> (16 + SHIFT);
            int lofs = sc[b] - so[b];
            int pos = lofs + atomicAdd(&sr[b], 1);
            buf[pos] = pk[j];
        }
    }
    __syncthreads();
    // phase 4: write out; consecutive p within a bucket -> consecutive global
    for (int p = tid; p < nE; p += 256) {
        unsigned int e = buf[p];
        int b = e >> (16 + SHIFT);
        int lofs = sc[b] - so[b];
        staging[gb[b] + (p - lofs)] = e;
    }
}

// ---------- merged dispatch: GEMM1 blocks + bucketsort blocks (independent work) ----------
// blocks [0, NGEMM1)            : layer-1 GEMM (K=128,N=64,BM=64,BK=32) + att dots, fp16 H out
// blocks [NGEMM1, NGEMM1+NBUCK) : per-bucket sort staging -> node-grouped srt + offs
// Their common consumer is k_node<64>, which needs BOTH outputs -> perfect pairing;
// GEMM blocks first so the long poles start early.
__global__ __launch_bounds__(256) void k_sortgemm(
        const unsigned int* __restrict__ staging, const int* __restrict__ boffs,
        int* __restrict__ offs, int* __restrict__ srt,
        const float* __restrict__ X, const float* __restrict__ W,
        const float* __restrict__ a_src, const float* __restrict__ a_dst,
        __half* __restrict__ H, float* __restrict__ as_, float* __restrict__ ad_) {
    const int tid = threadIdx.x;
    if (blockIdx.x >= NGEMM1) {
        // ----- bucketsort branch -----
        __shared__ int cnt[64];
        __shared__ int base[64];
        __shared__ int cur[64];
        const int b = blockIdx.x - NGEMM1;
        const int node0 = b << SHIFT;
        const int nn = min(64, N_NODES - node0);
        if (tid < 64) cnt[tid] = 0;
        __syncthreads();
        const int beg = boffs[b], end = boffs[b + 1];
        for (int i = beg + tid; i < end; i += 256)
            atomicAdd(&cnt[(staging[i] >> 16) - node0], 1);
        __syncthreads();
        if (tid < 64) {
            int v = cnt[tid];
            int incl = v;
#pragma unroll
            for (int off = 1; off < 64; off <<= 1) {
                int t = __shfl_up(incl, off, 64);
                if (tid >= off) incl += t;
            }
            base[tid] = beg + incl - v;
            cur[tid] = 0;
            if (tid < nn) offs[node0 + tid] = beg + incl - v;
        }
        __syncthreads();
        for (int i = beg + tid; i < end; i += 256) {
            unsigned int e = staging[i];
            int dl = (int)(e >> 16) - node0;
            int pos = base[dl] + atomicAdd(&cur[dl], 1);
            srt[pos] = (int)(e & 0xFFFFu);
        }
        if (b == 0 && tid == 0) offs[N_NODES] = boffs[NBUCK];
        return;
    }
    // ----- GEMM1 branch: K=128, N=64, BM=64, BK=32 -----
    constexpr int K = 128, N = 64, BM = 64, BK = 32;
    constexpr int TCOLS = N / 4;                 // 16
    constexpr int KPT = (BM * BK) / 256;         // 8
    __shared__ float Xs[BK][BM];
    __shared__ float Ws[BK][N];
    const int bid  = blockIdx.x;
    const int tcol = tid % TCOLS;
    const int trow = tid / TCOLS;
    const int node0 = bid * BM;
    const int r0 = trow * 4;
    const int c0 = tcol * 4;
    float acc[4][4] = {};

    const int sm = tid % BM;
    const int skb = (tid / BM) * KPT;
    const int srow = (node0 + sm < N_NODES) ? (node0 + sm) : (N_NODES - 1);

    for (int k0 = 0; k0 < K; k0 += BK) {
        const float* xp = X + (long long)srow * K + k0 + skb;
#pragma unroll
        for (int j = 0; j < KPT; j += 4) {
            float4 v = *(const float4*)(xp + j);
            Xs[skb + j + 0][sm] = v.x;
            Xs[skb + j + 1][sm] = v.y;
            Xs[skb + j + 2][sm] = v.z;
            Xs[skb + j + 3][sm] = v.w;
        }
#pragma unroll
        for (int i = tid; i < BK * N / 4; i += 256)
            ((float4*)Ws)[i] = ((const float4*)W)[(k0 * N) / 4 + i];
        __syncthreads();
#pragma unroll 8
        for (int k = 0; k < BK; ++k) {
            float4 xa = *(const float4*)&Xs[k][r0];
            float4 wb = *(const float4*)&Ws[k][c0];
            float xr[4] = {xa.x, xa.y, xa.z, xa.w};
            float wc[4] = {wb.x, wb.y, wb.z, wb.w};
#pragma unroll
            for (int i = 0; i < 4; ++i)
#pragma unroll
                for (int j = 0; j < 4; ++j)
                    acc[i][j] += xr[i] * wc[j];
        }
        __syncthreads();
    }

    const float4 asv = *(const float4*)(a_src + c0);
    const float4 adv = *(const float4*)(a_dst + c0);
    const int rbase = node0 + r0;
    float vsr[4], vdr[4];
#pragma unroll
    for (int i = 0; i < 4; ++i) {
        float vs = acc[i][0] * asv.x + acc[i][1] * asv.y + acc[i][2] * asv.z + acc[i][3] * asv.w;
        float vd = acc[i][0] * adv.x + acc[i][1] * adv.y + acc[i][2] * adv.z + acc[i][3] * adv.w;
#pragma unroll
        for (int off = 1; off < TCOLS; off <<= 1) {
            vs += __shfl_xor(vs, off, 64);
            vd += __shfl_xor(vd, off, 64);
        }
        vsr[i] = vs; vdr[i] = vd;
        if (rbase + i < N_NODES) {
            __half2 q0 = __floats2half2_rn(acc[i][0], acc[i][1]);
            __half2 q1 = __floats2half2_rn(acc[i][2], acc[i][3]);
            uint2 raw;
            raw.x = *(unsigned int*)&q0;
            raw.y = *(unsigned int*)&q1;
            *(uint2*)(H + (long long)(rbase + i) * N + c0) = raw;
        }
    }
    if (tcol == 0) {
#pragma unroll
        for (int i = 0; i < 4; ++i) {
            if (rbase + i < N_NODES) {
                as_[rbase + i] = vsr[i];
                ad_[rbase + i] = vdr[i];
            }
        }
    }
}

// ---------- register-tiled GEMM (H = X @ W, stored fp16) + attention dots (layer 2) ----------
template<int K, int N, int BM, int BK>
__global__ __launch_bounds__(256) void k_gemm_att(
        const float* __restrict__ X, const float* __restrict__ W,
        const float* __restrict__ a_src, const float* __restrict__ a_dst,
        __half* __restrict__ H, float* __restrict__ as_, float* __restrict__ ad_) {
    constexpr int TCOLS = N / 4;
    __shared__ float Xs[BK][BM];
    __shared__ float Ws[BK][N];
    const int tid  = threadIdx.x;
    const int tcol = tid % TCOLS;
    const int trow = tid / TCOLS;
    const int node0 = blockIdx.x * BM;
    const int r0 = trow * 4;
    const int c0 = tcol * 4;
    float acc[4][4] = {};

    constexpr int KPT = (BM * BK) / 256;
    const int sm = tid % BM;
    const int skb = (tid / BM) * KPT;
    const int srow = (node0 + sm < N_NODES) ? (node0 + sm) : (N_NODES - 1);

    for (int k0 = 0; k0 < K; k0 += BK) {
        const float* xp = X + (long long)srow * K + k0 + skb;
#pragma unroll
        for (int j = 0; j < KPT; j += 4) {
            float4 v = *(const float4*)(xp + j);
            Xs[skb + j + 0][sm] = v.x;
            Xs[skb + j + 1][sm] = v.y;
            Xs[skb + j + 2][sm] = v.z;
            Xs[skb + j + 3][sm] = v.w;
        }
#pragma unroll
        for (int i = tid; i < BK * N / 4; i += 256)
            ((float4*)Ws)[i] = ((const float4*)W)[(k0 * N) / 4 + i];
        __syncthreads();
#pragma unroll 8
        for (int k = 0; k < BK; ++k) {
            float4 xa = *(const float4*)&Xs[k][r0];
            float4 wb = *(const float4*)&Ws[k][c0];
            float xr[4] = {xa.x, xa.y, xa.z, xa.w};
            float wc[4] = {wb.x, wb.y, wb.z, wb.w};
#pragma unroll
            for (int i = 0; i < 4; ++i)
#pragma unroll
                for (int j = 0; j < 4; ++j)
                    acc[i][j] += xr[i] * wc[j];
        }
        __syncthreads();
    }

    const float4 asv = *(const float4*)(a_src + c0);
    const float4 adv = *(const float4*)(a_dst + c0);
    const int rbase = node0 + r0;
    float vsr[4], vdr[4];
#pragma unroll
    for (int i = 0; i < 4; ++i) {
        float vs = acc[i][0] * asv.x + acc[i][1] * asv.y + acc[i][2] * asv.z + acc[i][3] * asv.w;
        float vd = acc[i][0] * adv.x + acc[i][1] * adv.y + acc[i][2] * adv.z + acc[i][3] * adv.w;
#pragma unroll
        for (int off = 1; off < TCOLS; off <<= 1) {
            vs += __shfl_xor(vs, off, 64);
            vd += __shfl_xor(vd, off, 64);
        }
        vsr[i] = vs; vdr[i] = vd;
        if (rbase + i < N_NODES) {
            __half2 q0 = __floats2half2_rn(acc[i][0], acc[i][1]);
            __half2 q1 = __floats2half2_rn(acc[i][2], acc[i][3]);
            uint2 raw;
            raw.x = *(unsigned int*)&q0;
            raw.y = *(unsigned int*)&q1;
            *(uint2*)(H + (long long)(rbase + i) * N + c0) = raw;
        }
    }
    if (tcol == 0) {
#pragma unroll
        for (int i = 0; i < 4; ++i) {
            if (rbase + i < N_NODES) {
                as_[rbase + i] = vsr[i];
                ad_[rbase + i] = vdr[i];
            }
        }
    }
}

// ---------- fused per-node single pass: two-phase, fp16 H gather (uint4 row loads) ----------
// ONE WAVE PER NODE.
// Phase A: one edge per lane -> coalesced srt load, one as_ gather instr per 64 edges,
//          wave-parallel leakyrelu+exp (fixed shift MB_SHIFT); p in registers.
// Phase B: (src, p) broadcast via __shfl; each lane loads 8 halfs with ONE uint4 (16B)
//          -> G=C/8 lanes/row, NG=64/G rows per iteration, 2x unrolled.
template<int C, bool ELU>
__global__ __launch_bounds__(256) void k_node(
        const int* __restrict__ offs, const int* __restrict__ srt,
        const float* __restrict__ as_, const float* __restrict__ ad_,
        const __half* __restrict__ H, const float* __restrict__ bias,
        float* __restrict__ out) {
    constexpr int G  = C / 8;    // lanes per row (8 for C=64, 4 for C=32)
    constexpr int NG = 64 / G;   // rows gathered per iteration (8 or 16)
    const int node = (int)(((long long)blockIdx.x * blockDim.x + threadIdx.x) >> 6);
    if (node >= N_NODES) return;
    const int lane = threadIdx.x & 63;
    const int g  = lane / G;
    const int cl = lane % G;
    const int beg = offs[node], end = offs[node + 1];
    const int deg = end - beg;
    const float adn = ad_[node];
    float acc[8] = {};
    float ssum = 0.f;

    for (int base = 0; base < deg; base += 64) {
        const int nb = min(64, deg - base);
        // ---- phase A: one edge per lane ----
        int s = 0;
        float p = 0.f;
        if (lane < nb) {
            s = srt[beg + base + lane];
            float e = as_[s] + adn;
            e = (e > 0.f) ? e : NEG_SLOPE * e;
            p = __expf(e - MB_SHIFT);
        }
        ssum += p;
        // ---- phase B: gather-only loop; lanes with index >= nb carry p=0 (benign row-0 read) ----
        int j = 0;
        for (; j + NG < nb; j += 2 * NG) {
            const int i0 = j + g, i1 = j + NG + g;
            const int   s0 = __shfl(s, i0, 64);
            const int   s1 = __shfl(s, i1, 64);
            const float p0 = __shfl(p, i0, 64);
            const float p1 = __shfl(p, i1, 64);
            const uint4 ra = *(const uint4*)(H + (long long)s0 * C + cl * 8);
            const uint4 rb = *(const uint4*)(H + (long long)s1 * C + cl * 8);
            float2 f;
            f = __half22float2(*(const __half2*)&ra.x); acc[0] += p0 * f.x; acc[1] += p0 * f.y;
            f = __half22float2(*(const __half2*)&ra.y); acc[2] += p0 * f.x; acc[3] += p0 * f.y;
            f = __half22float2(*(const __half2*)&ra.z); acc[4] += p0 * f.x; acc[5] += p0 * f.y;
            f = __half22float2(*(const __half2*)&ra.w); acc[6] += p0 * f.x; acc[7] += p0 * f.y;
            f = __half22float2(*(const __half2*)&rb.x); acc[0] += p1 * f.x; acc[1] += p1 * f.y;
            f = __half22float2(*(const __half2*)&rb.y); acc[2] += p1 * f.x; acc[3] += p1 * f.y;
            f = __half22float2(*(const __half2*)&rb.z); acc[4] += p1 * f.x; acc[5] += p1 * f.y;
            f = __half22float2(*(const __half2*)&rb.w); acc[6] += p1 * f.x; acc[7] += p1 * f.y;
        }
        if (j < nb) {
            const int i0 = j + g;
            const int   s0 = __shfl(s, i0, 64);
            const float p0 = __shfl(p, i0, 64);
            const uint4 ra = *(const uint4*)(H + (long long)s0 * C + cl * 8);
            float2 f;
            f = __half22float2(*(const __half2*)&ra.x); acc[0] += p0 * f.x; acc[1] += p0 * f.y;
            f = __half22float2(*(const __half2*)&ra.y); acc[2] += p0 * f.x; acc[3] += p0 * f.y;
            f = __half22float2(*(const __half2*)&ra.z); acc[4] += p0 * f.x; acc[5] += p0 * f.y;
            f = __half22float2(*(const __half2*)&ra.w); acc[6] += p0 * f.x; acc[7] += p0 * f.y;
        }
    }
    // ssum: full 64-lane reduce (phase A spread p across all lanes)
#pragma unroll
    for (int off = 1; off < 64; off <<= 1)
        ssum += __shfl_xor(ssum, off, 64);
    // acc: reduce across the NG row-groups
#pragma unroll
    for (int off = G; off < 64; off <<= 1)
#pragma unroll
        for (int q = 0; q < 8; q++)
            acc[q] += __shfl_xor(acc[q], off, 64);
    if (lane < G) {
        const float inv = 1.f / (ssum + 1e-30f);
        float v[8];
#pragma unroll
        for (int q = 0; q < 8; q++) {
            v[q] = acc[q] * inv + bias[cl * 8 + q];
            if (ELU) v[q] = (v[q] > 0.f) ? v[q] : expm1f(v[q]);
        }
        float4 lo = {v[0], v[1], v[2], v[3]};
        float4 hi = {v[4], v[5], v[6], v[7]};
        *(float4*)(out + (long long)node * C + cl * 8)     = lo;
        *(float4*)(out + (long long)node * C + cl * 8 + 4) = hi;
    }
}

extern "C" void kernel_launch(void* const* d_in, const int* in_sizes, int n_in,
                              void* d_out, int out_size, void* d_ws, size_t ws_size,
                              hipStream_t stream) {
    const float* x      = (const float*)d_in[0];
    const void*  edges  = d_in[1];
    const float* W1     = (const float*)d_in[2];
    const float* a_src1 = (const float*)d_in[3];
    const float* a_dst1 = (const float*)d_in[4];
    const float* b1     = (const float*)d_in[5];
    const float* W2     = (const float*)d_in[6];
    const float* a_src2 = (const float*)d_in[7];
    const float* a_dst2 = (const float*)d_in[8];
    const float* b2     = (const float*)d_in[9];

    char* ws = (char*)d_ws;
    size_t off = 0;
    auto alloc = [&](size_t bytes) { char* p = ws + off; off += (bytes + 255) & ~size_t(255); return p; };
    __half*       h1      = (__half*)      alloc((size_t)N_NODES * 64 * 2);  // fp16 H, layer 1
    float*        h2      = (float*)       alloc((size_t)N_NODES * 64 * 4);  // layer-1 out (fp32)
    float*        as1     = (float*)       alloc((size_t)N_NODES * 4);
    float*        ad1     = (float*)       alloc((size_t)N_NODES * 4);
    float*        as2     = (float*)       alloc((size_t)N_NODES * 4);
    float*        ad2     = (float*)       alloc((size_t)N_NODES * 4);
    int*          part    = (int*)         alloc((size_t)HPART * NBUCK * 4);
    int*          boffs   = (int*)         alloc((size_t)(NBUCK + 1) * 4);
    int*          gcur    = (int*)         alloc((size_t)NBUCK * 4);
    int*          offs    = (int*)         alloc((size_t)(N_NODES + 1) * 4);
    unsigned int* staging = (unsigned int*)alloc((size_t)TOT_E * 4);
    int*          srt     = (int*)         alloc((size_t)(TOT_E + 8) * 4);
    float*        out     = (float*)d_out;
    __half*       g2      = h1;  // h1 dead after k_node<64>; reuse (3.2MB needed < 6.4MB)

    const int NODE_BLOCKS = (N_NODES * 64 + 255) / 256;  // one wave per node

    // binned CSR build front (no k_init: partial hists need no zeroed global,
    // edge dtype detected per-block via ballot)
    k_binhist<<<HPART, 256, 0, stream>>>(edges, part);
    k_bscan<<<1, 256, 0, stream>>>(part, boffs, gcur);
    k_binscatter<<<NCHUNK, 256, 0, stream>>>(edges, gcur, staging);

    // merged: layer-1 GEMM (independent) + bucketsort (needs binscatter) in ONE dispatch;
    // both outputs feed k_node<64>.
    k_sortgemm<<<NGEMM1 + NBUCK, 256, 0, stream>>>(
        staging, boffs, offs, srt, x, W1, a_src1, a_dst1, h1, as1, ad1);
    k_node<64, true><<<NODE_BLOCKS, 256, 0, stream>>>(offs, srt, as1, ad1, h1, b1, h2);

    // layer 2: K=64, N=32, BM=128, BK=32
    k_gemm_att<64, 32, 128, 32><<<(N_NODES + 127) / 128, 256, 0, stream>>>(
        h2, W2, a_src2, a_dst2, g2, as2, ad2);
    k_node<32, false><<<NODE_BLOCKS, 256, 0, stream>>>(offs, srt, as2, ad2, g2, b2, out);
}

// Round 5
// 137.008 us; speedup vs baseline: 1.1428x; 1.1428x over previous
//
#include <hip/hip_runtime.h>
#include <hip/hip_fp16.h>

#define N_NODES 50000
#define N_EDGES 800000
#define TOT_E   (N_EDGES + N_NODES)
#define NEG_SLOPE 0.2f
#define MB_SHIFT 8.0f   // fixed softmax shift: valid upper bound for e=as+ad (|e|<~3);
                        // softmax is shift-invariant so result is exact up to fp rounding.

#define SHIFT  6
#define NBUCK  ((N_NODES + 63) >> SHIFT)       // 782 buckets of 64 nodes
#define NBP    1024                             // padded scan width
#define CHUNK  4096                             // 208 binscatter blocks
#define EPT    (CHUNK / 256)                    // 16 edges per thread
#define NCHUNK ((TOT_E + CHUNK - 1) / CHUNK)
#define NGEMM1 ((N_NODES + 63) / 64)            // 782 GEMM1 blocks (BM=64)

// ---------- edge fetch (handles int32 or int64 edge_index; self-loops appended) ----------
__device__ __forceinline__ void get_edge(const void* edges, int flag64, long long i,
                                         int& src, int& dst) {
    if (i < N_EDGES) {
        if (flag64) {
            const long long* e = (const long long*)edges;
            src = (int)e[i];
            dst = (int)e[N_EDGES + i];
        } else {
            const int* e = (const int*)edges;
            src = e[i];
            dst = e[(long long)N_EDGES + i];
        }
    } else {
        src = dst = (int)(i - N_EDGES);
    }
}

__device__ __forceinline__ int get_dst(const void* edges, int flag64, long long i) {
    if (i < N_EDGES) {
        if (flag64) return (int)((const long long*)edges)[N_EDGES + i];
        return ((const int*)edges)[(long long)N_EDGES + i];
    }
    return (int)(i - N_EDGES);
}

// per-block edge-dtype detection: wave 0 checks first 64 int64 slots, one ballot.
// (int32 data reinterpreted as int64 lands outside [0,N_NODES) unless every high
// word is 0 -- probability ~0 for random ids; same heuristic as the old k_init.)
__device__ __forceinline__ int detect64(const void* edges, int tid, int* sfl) {
    if (tid < 64) {
        long long v = ((const long long*)edges)[tid];
        unsigned long long ok = __ballot(v >= 0 && v < N_NODES);
        if (tid == 0) *sfl = (ok == ~0ull) ? 1 : 0;
    }
    __syncthreads();
    return *sfl;
}

// ---------- zero the global bucket histogram (3KB) ----------
__global__ __launch_bounds__(256) void k_zero(int* __restrict__ ghist) {
    int i = blockIdx.x * blockDim.x + threadIdx.x;
    if (i < NBUCK) ghist[i] = 0;
}

// ---------- bucket histogram: 416 blocks, LDS-aggregated, global atomic flush ----------
// (HPART=32 partial-hist variant measured 49.6us at 1% occupancy -- reverted to this
//  416-block form which was <5us in rounds 0-3.)
__global__ __launch_bounds__(256) void k_binhist(const void* edges, int* __restrict__ ghist) {
    __shared__ int h[NBUCK];
    __shared__ int sfl;
    const int tid = threadIdx.x;
    for (int i = tid; i < NBUCK; i += 256) h[i] = 0;
    const int fl = detect64(edges, tid, &sfl);   // includes __syncthreads()
    const int stride = gridDim.x * blockDim.x;
    for (long long i = (long long)blockIdx.x * blockDim.x + tid; i < TOT_E; i += stride)
        atomicAdd(&h[get_dst(edges, fl, i) >> SHIFT], 1);
    __syncthreads();
    for (int i = tid; i < NBUCK; i += 256)
        if (h[i]) atomicAdd(&ghist[i], h[i]);
}

// ---------- single-block scan of bucket histogram -> boffs, gcur ----------
__global__ __launch_bounds__(256) void k_bscan(const int* __restrict__ ghist,
                                               int* __restrict__ boffs,
                                               int* __restrict__ gcur) {
    __shared__ int sc[NBP];
    const int tid = threadIdx.x;
    for (int s = 0; s < 4; s++) {
        int i = tid + s * 256;
        sc[i] = (i < NBUCK) ? ghist[i] : 0;
    }
    __syncthreads();
    for (int off = 1; off < NBP; off <<= 1) {
        int t[4];
        for (int s = 0; s < 4; s++) {
            int a = tid + s * 256;
            t[s] = (a >= off) ? sc[a - off] : 0;
        }
        __syncthreads();
        for (int s = 0; s < 4; s++) sc[tid + s * 256] += t[s];
        __syncthreads();
    }
    for (int s = 0; s < 4; s++) {
        int i = tid + s * 256;
        if (i < NBUCK) {
            int e = sc[i] - ghist[i];   // exclusive
            boffs[i] = e;
            gcur[i]  = e;
        }
    }
    if (tid == 0) boffs[NBUCK] = sc[NBUCK - 1];
}

// ---------- chunked binscatter: group chunk's edges by bucket in LDS, write runs ----------
__global__ __launch_bounds__(256) void k_binscatter(const void* edges,
                                                    int* gcur, unsigned int* staging) {
    __shared__ int sc[NBP];        // counts -> inclusive scan
    __shared__ int so[NBP];        // original counts
    __shared__ int sr[NBUCK];      // running cursor (phase 3)
    __shared__ int gb[NBUCK];      // global base per bucket
    __shared__ unsigned int buf[CHUNK];
    __shared__ int sfl;
    const int tid = threadIdx.x;
    const int c0 = blockIdx.x * CHUNK;
    const int nE = min(CHUNK, TOT_E - c0);
    unsigned int pk[EPT];

    for (int s = 0; s < 4; s++) sc[tid + s * 256] = 0;
    for (int i = tid; i < NBUCK; i += 256) sr[i] = 0;
    const int fl = detect64(edges, tid, &sfl);   // includes __syncthreads()
    // phase 1: read edges, pack, count
#pragma unroll
    for (int j = 0; j < EPT; j++) {
        int li = j * 256 + tid;
        pk[j] = 0u;
        if (li < nE) {
            int src, dst;
            get_edge(edges, fl, (long long)(c0 + li), src, dst);
            pk[j] = ((unsigned int)dst << 16) | (unsigned int)src;
            atomicAdd(&sc[dst >> SHIFT], 1);
        }
    }
    __syncthreads();
    for (int s = 0; s < 4; s++) { int i = tid + s * 256; so[i] = sc[i]; }
    __syncthreads();
    // phase 2: inclusive scan of sc
    for (int off = 1; off < NBP; off <<= 1) {
        int t[4];
        for (int s = 0; s < 4; s++) {
            int a = tid + s * 256;
            t[s] = (a >= off) ? sc[a - off] : 0;
        }
        __syncthreads();
        for (int s = 0; s < 4; s++) sc[tid + s * 256] += t[s];
        __syncthreads();
    }
    // reserve global ranges
    for (int b = tid; b < NBUCK; b += 256)
        if (so[b]) gb[b] = atomicAdd(&gcur[b], so[b]);
    __syncthreads();
    // phase 3: place packed edges bucket-grouped in LDS
#pragma unroll
    for (int j = 0; j < EPT; j++) {
        int li = j * 256 + tid;
        if (li < nE) {
            int b = pk[j] >> (16 + SHIFT);
            int lofs = sc[b] - so[b];
            int pos = lofs + atomicAdd(&sr[b], 1);
            buf[pos] = pk[j];
        }
    }
    __syncthreads();
    // phase 4: write out; consecutive p within a bucket -> consecutive global
    for (int p = tid; p < nE; p += 256) {
        unsigned int e = buf[p];
        int b = e >> (16 + SHIFT);
        int lofs = sc[b] - so[b];
        staging[gb[b] + (p - lofs)] = e;
    }
}

// ---------- merged dispatch: GEMM1 blocks + bucketsort blocks (independent work) ----------
// blocks [0, NGEMM1)            : layer-1 GEMM (K=128,N=64,BM=64,BK=32) + att dots, fp16 H out
// blocks [NGEMM1, NGEMM1+NBUCK) : per-bucket sort staging -> node-grouped srt + offs
// Their common consumer is k_node<64>, which needs BOTH outputs -> perfect pairing;
// GEMM blocks first so the long poles start early.
__global__ __launch_bounds__(256) void k_sortgemm(
        const unsigned int* __restrict__ staging, const int* __restrict__ boffs,
        int* __restrict__ offs, int* __restrict__ srt,
        const float* __restrict__ X, const float* __restrict__ W,
        const float* __restrict__ a_src, const float* __restrict__ a_dst,
        __half* __restrict__ H, float* __restrict__ as_, float* __restrict__ ad_) {
    const int tid = threadIdx.x;
    if (blockIdx.x >= NGEMM1) {
        // ----- bucketsort branch -----
        __shared__ int cnt[64];
        __shared__ int base[64];
        __shared__ int cur[64];
        const int b = blockIdx.x - NGEMM1;
        const int node0 = b << SHIFT;
        const int nn = min(64, N_NODES - node0);
        if (tid < 64) cnt[tid] = 0;
        __syncthreads();
        const int beg = boffs[b], end = boffs[b + 1];
        for (int i = beg + tid; i < end; i += 256)
            atomicAdd(&cnt[(staging[i] >> 16) - node0], 1);
        __syncthreads();
        if (tid < 64) {
            int v = cnt[tid];
            int incl = v;
#pragma unroll
            for (int off = 1; off < 64; off <<= 1) {
                int t = __shfl_up(incl, off, 64);
                if (tid >= off) incl += t;
            }
            base[tid] = beg + incl - v;
            cur[tid] = 0;
            if (tid < nn) offs[node0 + tid] = beg + incl - v;
        }
        __syncthreads();
        for (int i = beg + tid; i < end; i += 256) {
            unsigned int e = staging[i];
            int dl = (int)(e >> 16) - node0;
            int pos = base[dl] + atomicAdd(&cur[dl], 1);
            srt[pos] = (int)(e & 0xFFFFu);
        }
        if (b == 0 && tid == 0) offs[N_NODES] = boffs[NBUCK];
        return;
    }
    // ----- GEMM1 branch: K=128, N=64, BM=64, BK=32 -----
    constexpr int K = 128, N = 64, BM = 64, BK = 32;
    constexpr int TCOLS = N / 4;                 // 16
    constexpr int KPT = (BM * BK) / 256;         // 8
    __shared__ float Xs[BK][BM];
    __shared__ float Ws[BK][N];
    const int bid  = blockIdx.x;
    const int tcol = tid % TCOLS;
    const int trow = tid / TCOLS;
    const int node0 = bid * BM;
    const int r0 = trow * 4;
    const int c0 = tcol * 4;
    float acc[4][4] = {};

    const int sm = tid % BM;
    const int skb = (tid / BM) * KPT;
    const int srow = (node0 + sm < N_NODES) ? (node0 + sm) : (N_NODES - 1);

    for (int k0 = 0; k0 < K; k0 += BK) {
        const float* xp = X + (long long)srow * K + k0 + skb;
#pragma unroll
        for (int j = 0; j < KPT; j += 4) {
            float4 v = *(const float4*)(xp + j);
            Xs[skb + j + 0][sm] = v.x;
            Xs[skb + j + 1][sm] = v.y;
            Xs[skb + j + 2][sm] = v.z;
            Xs[skb + j + 3][sm] = v.w;
        }
#pragma unroll
        for (int i = tid; i < BK * N / 4; i += 256)
            ((float4*)Ws)[i] = ((const float4*)W)[(k0 * N) / 4 + i];
        __syncthreads();
#pragma unroll 8
        for (int k = 0; k < BK; ++k) {
            float4 xa = *(const float4*)&Xs[k][r0];
            float4 wb = *(const float4*)&Ws[k][c0];
            float xr[4] = {xa.x, xa.y, xa.z, xa.w};
            float wc[4] = {wb.x, wb.y, wb.z, wb.w};
#pragma unroll
            for (int i = 0; i < 4; ++i)
#pragma unroll
                for (int j = 0; j < 4; ++j)
                    acc[i][j] += xr[i] * wc[j];
        }
        __syncthreads();
    }

    const float4 asv = *(const float4*)(a_src + c0);
    const float4 adv = *(const float4*)(a_dst + c0);
    const int rbase = node0 + r0;
    float vsr[4], vdr[4];
#pragma unroll
    for (int i = 0; i < 4; ++i) {
        float vs = acc[i][0] * asv.x + acc[i][1] * asv.y + acc[i][2] * asv.z + acc[i][3] * asv.w;
        float vd = acc[i][0] * adv.x + acc[i][1] * adv.y + acc[i][2] * adv.z + acc[i][3] * adv.w;
#pragma unroll
        for (int off = 1; off < TCOLS; off <<= 1) {
            vs += __shfl_xor(vs, off, 64);
            vd += __shfl_xor(vd, off, 64);
        }
        vsr[i] = vs; vdr[i] = vd;
        if (rbase + i < N_NODES) {
            __half2 q0 = __floats2half2_rn(acc[i][0], acc[i][1]);
            __half2 q1 = __floats2half2_rn(acc[i][2], acc[i][3]);
            uint2 raw;
            raw.x = *(unsigned int*)&q0;
            raw.y = *(unsigned int*)&q1;
            *(uint2*)(H + (long long)(rbase + i) * N + c0) = raw;
        }
    }
    if (tcol == 0) {
#pragma unroll
        for (int i = 0; i < 4; ++i) {
            if (rbase + i < N_NODES) {
                as_[rbase + i] = vsr[i];
                ad_[rbase + i] = vdr[i];
            }
        }
    }
}

// ---------- register-tiled GEMM (H = X @ W, stored fp16) + attention dots (layer 2) ----------
template<int K, int N, int BM, int BK>
__global__ __launch_bounds__(256) void k_gemm_att(
        const float* __restrict__ X, const float* __restrict__ W,
        const float* __restrict__ a_src, const float* __restrict__ a_dst,
        __half* __restrict__ H, float* __restrict__ as_, float* __restrict__ ad_) {
    constexpr int TCOLS = N / 4;
    __shared__ float Xs[BK][BM];
    __shared__ float Ws[BK][N];
    const int tid  = threadIdx.x;
    const int tcol = tid % TCOLS;
    const int trow = tid / TCOLS;
    const int node0 = blockIdx.x * BM;
    const int r0 = trow * 4;
    const int c0 = tcol * 4;
    float acc[4][4] = {};

    constexpr int KPT = (BM * BK) / 256;
    const int sm = tid % BM;
    const int skb = (tid / BM) * KPT;
    const int srow = (node0 + sm < N_NODES) ? (node0 + sm) : (N_NODES - 1);

    for (int k0 = 0; k0 < K; k0 += BK) {
        const float* xp = X + (long long)srow * K + k0 + skb;
#pragma unroll
        for (int j = 0; j < KPT; j += 4) {
            float4 v = *(const float4*)(xp + j);
            Xs[skb + j + 0][sm] = v.x;
            Xs[skb + j + 1][sm] = v.y;
            Xs[skb + j + 2][sm] = v.z;
            Xs[skb + j + 3][sm] = v.w;
        }
#pragma unroll
        for (int i = tid; i < BK * N / 4; i += 256)
            ((float4*)Ws)[i] = ((const float4*)W)[(k0 * N) / 4 + i];
        __syncthreads();
#pragma unroll 8
        for (int k = 0; k < BK; ++k) {
            float4 xa = *(const float4*)&Xs[k][r0];
            float4 wb = *(const float4*)&Ws[k][c0];
            float xr[4] = {xa.x, xa.y, xa.z, xa.w};
            float wc[4] = {wb.x, wb.y, wb.z, wb.w};
#pragma unroll
            for (int i = 0; i < 4; ++i)
#pragma unroll
                for (int j = 0; j < 4; ++j)
                    acc[i][j] += xr[i] * wc[j];
        }
        __syncthreads();
    }

    const float4 asv = *(const float4*)(a_src + c0);
    const float4 adv = *(const float4*)(a_dst + c0);
    const int rbase = node0 + r0;
    float vsr[4], vdr[4];
#pragma unroll
    for (int i = 0; i < 4; ++i) {
        float vs = acc[i][0] * asv.x + acc[i][1] * asv.y + acc[i][2] * asv.z + acc[i][3] * asv.w;
        float vd = acc[i][0] * adv.x + acc[i][1] * adv.y + acc[i][2] * adv.z + acc[i][3] * adv.w;
#pragma unroll
        for (int off = 1; off < TCOLS; off <<= 1) {
            vs += __shfl_xor(vs, off, 64);
            vd += __shfl_xor(vd, off, 64);
        }
        vsr[i] = vs; vdr[i] = vd;
        if (rbase + i < N_NODES) {
            __half2 q0 = __floats2half2_rn(acc[i][0], acc[i][1]);
            __half2 q1 = __floats2half2_rn(acc[i][2], acc[i][3]);
            uint2 raw;
            raw.x = *(unsigned int*)&q0;
            raw.y = *(unsigned int*)&q1;
            *(uint2*)(H + (long long)(rbase + i) * N + c0) = raw;
        }
    }
    if (tcol == 0) {
#pragma unroll
        for (int i = 0; i < 4; ++i) {
            if (rbase + i < N_NODES) {
                as_[rbase + i] = vsr[i];
                ad_[rbase + i] = vdr[i];
            }
        }
    }
}

// ---------- fused per-node single pass: two-phase, fp16 H gather (uint4 row loads) ----------
// ONE WAVE PER NODE.
// Phase A: one edge per lane -> coalesced srt load, one as_ gather instr per 64 edges,
//          wave-parallel leakyrelu+exp (fixed shift MB_SHIFT); p in registers.
// Phase B: (src, p) broadcast via __shfl; each lane loads 8 halfs with ONE uint4 (16B)
//          -> G=C/8 lanes/row, NG=64/G rows per iteration, 2x unrolled.
template<int C, bool ELU>
__global__ __launch_bounds__(256) void k_node(
        const int* __restrict__ offs, const int* __restrict__ srt,
        const float* __restrict__ as_, const float* __restrict__ ad_,
        const __half* __restrict__ H, const float* __restrict__ bias,
        float* __restrict__ out) {
    constexpr int G  = C / 8;    // lanes per row (8 for C=64, 4 for C=32)
    constexpr int NG = 64 / G;   // rows gathered per iteration (8 or 16)
    const int node = (int)(((long long)blockIdx.x * blockDim.x + threadIdx.x) >> 6);
    if (node >= N_NODES) return;
    const int lane = threadIdx.x & 63;
    const int g  = lane / G;
    const int cl = lane % G;
    const int beg = offs[node], end = offs[node + 1];
    const int deg = end - beg;
    const float adn = ad_[node];
    float acc[8] = {};
    float ssum = 0.f;

    for (int base = 0; base < deg; base += 64) {
        const int nb = min(64, deg - base);
        // ---- phase A: one edge per lane ----
        int s = 0;
        float p = 0.f;
        if (lane < nb) {
            s = srt[beg + base + lane];
            float e = as_[s] + adn;
            e = (e > 0.f) ? e : NEG_SLOPE * e;
            p = __expf(e - MB_SHIFT);
        }
        ssum += p;
        // ---- phase B: gather-only loop; lanes with index >= nb carry p=0 (benign row-0 read) ----
        int j = 0;
        for (; j + NG < nb; j += 2 * NG) {
            const int i0 = j + g, i1 = j + NG + g;
            const int   s0 = __shfl(s, i0, 64);
            const int   s1 = __shfl(s, i1, 64);
            const float p0 = __shfl(p, i0, 64);
            const float p1 = __shfl(p, i1, 64);
            const uint4 ra = *(const uint4*)(H + (long long)s0 * C + cl * 8);
            const uint4 rb = *(const uint4*)(H + (long long)s1 * C + cl * 8);
            float2 f;
            f = __half22float2(*(const __half2*)&ra.x); acc[0] += p0 * f.x; acc[1] += p0 * f.y;
            f = __half22float2(*(const __half2*)&ra.y); acc[2] += p0 * f.x; acc[3] += p0 * f.y;
            f = __half22float2(*(const __half2*)&ra.z); acc[4] += p0 * f.x; acc[5] += p0 * f.y;
            f = __half22float2(*(const __half2*)&ra.w); acc[6] += p0 * f.x; acc[7] += p0 * f.y;
            f = __half22float2(*(const __half2*)&rb.x); acc[0] += p1 * f.x; acc[1] += p1 * f.y;
            f = __half22float2(*(const __half2*)&rb.y); acc[2] += p1 * f.x; acc[3] += p1 * f.y;
            f = __half22float2(*(const __half2*)&rb.z); acc[4] += p1 * f.x; acc[5] += p1 * f.y;
            f = __half22float2(*(const __half2*)&rb.w); acc[6] += p1 * f.x; acc[7] += p1 * f.y;
        }
        if (j < nb) {
            const int i0 = j + g;
            const int   s0 = __shfl(s, i0, 64);
            const float p0 = __shfl(p, i0, 64);
            const uint4 ra = *(const uint4*)(H + (long long)s0 * C + cl * 8);
            float2 f;
            f = __half22float2(*(const __half2*)&ra.x); acc[0] += p0 * f.x; acc[1] += p0 * f.y;
            f = __half22float2(*(const __half2*)&ra.y); acc[2] += p0 * f.x; acc[3] += p0 * f.y;
            f = __half22float2(*(const __half2*)&ra.z); acc[4] += p0 * f.x; acc[5] += p0 * f.y;
            f = __half22float2(*(const __half2*)&ra.w); acc[6] += p0 * f.x; acc[7] += p0 * f.y;
        }
    }
    // ssum: full 64-lane reduce (phase A spread p across all lanes)
#pragma unroll
    for (int off = 1; off < 64; off <<= 1)
        ssum += __shfl_xor(ssum, off, 64);
    // acc: reduce across the NG row-groups
#pragma unroll
    for (int off = G; off < 64; off <<= 1)
#pragma unroll
        for (int q = 0; q < 8; q++)
            acc[q] += __shfl_xor(acc[q], off, 64);
    if (lane < G) {
        const float inv = 1.f / (ssum + 1e-30f);
        float v[8];
#pragma unroll
        for (int q = 0; q < 8; q++) {
            v[q] = acc[q] * inv + bias[cl * 8 + q];
            if (ELU) v[q] = (v[q] > 0.f) ? v[q] : expm1f(v[q]);
        }
        float4 lo = {v[0], v[1], v[2], v[3]};
        float4 hi = {v[4], v[5], v[6], v[7]};
        *(float4*)(out + (long long)node * C + cl * 8)     = lo;
        *(float4*)(out + (long long)node * C + cl * 8 + 4) = hi;
    }
}

extern "C" void kernel_launch(void* const* d_in, const int* in_sizes, int n_in,
                              void* d_out, int out_size, void* d_ws, size_t ws_size,
                              hipStream_t stream) {
    const float* x      = (const float*)d_in[0];
    const void*  edges  = d_in[1];
    const float* W1     = (const float*)d_in[2];
    const float* a_src1 = (const float*)d_in[3];
    const float* a_dst1 = (const float*)d_in[4];
    const float* b1     = (const float*)d_in[5];
    const float* W2     = (const float*)d_in[6];
    const float* a_src2 = (const float*)d_in[7];
    const float* a_dst2 = (const float*)d_in[8];
    const float* b2     = (const float*)d_in[9];

    char* ws = (char*)d_ws;
    size_t off = 0;
    auto alloc = [&](size_t bytes) { char* p = ws + off; off += (bytes + 255) & ~size_t(255); return p; };
    __half*       h1      = (__half*)      alloc((size_t)N_NODES * 64 * 2);  // fp16 H, layer 1
    float*        h2      = (float*)       alloc((size_t)N_NODES * 64 * 4);  // layer-1 out (fp32)
    float*        as1     = (float*)       alloc((size_t)N_NODES * 4);
    float*        ad1     = (float*)       alloc((size_t)N_NODES * 4);
    float*        as2     = (float*)       alloc((size_t)N_NODES * 4);
    float*        ad2     = (float*)       alloc((size_t)N_NODES * 4);
    int*          ghist   = (int*)         alloc((size_t)NBUCK * 4);
    int*          boffs   = (int*)         alloc((size_t)(NBUCK + 1) * 4);
    int*          gcur    = (int*)         alloc((size_t)NBUCK * 4);
    int*          offs    = (int*)         alloc((size_t)(N_NODES + 1) * 4);
    unsigned int* staging = (unsigned int*)alloc((size_t)TOT_E * 4);
    int*          srt     = (int*)         alloc((size_t)(TOT_E + 8) * 4);
    float*        out     = (float*)d_out;
    __half*       g2      = h1;  // h1 dead after k_node<64>; reuse (3.2MB needed < 6.4MB)

    const int NODE_BLOCKS = (N_NODES * 64 + 255) / 256;  // one wave per node

    // binned CSR build front (zero + 416-block atomic histogram: measured-fast form)
    k_zero<<<(NBUCK + 255) / 256, 256, 0, stream>>>(ghist);
    k_binhist<<<416, 256, 0, stream>>>(edges, ghist);
    k_bscan<<<1, 256, 0, stream>>>(ghist, boffs, gcur);
    k_binscatter<<<NCHUNK, 256, 0, stream>>>(edges, gcur, staging);

    // merged: layer-1 GEMM (independent) + bucketsort (needs binscatter) in ONE dispatch;
    // both outputs feed k_node<64>.
    k_sortgemm<<<NGEMM1 + NBUCK, 256, 0, stream>>>(
        staging, boffs, offs, srt, x, W1, a_src1, a_dst1, h1, as1, ad1);
    k_node<64, true><<<NODE_BLOCKS, 256, 0, stream>>>(offs, srt, as1, ad1, h1, b1, h2);

    // layer 2: K=64, N=32, BM=128, BK=32
    k_gemm_att<64, 32, 128, 32><<<(N_NODES + 127) / 128, 256, 0, stream>>>(
        h2, W2, a_src2, a_dst2, g2, as2, ad2);
    k_node<32, false><<<NODE_BLOCKS, 256, 0, stream>>>(offs, srt, as2, ad2, g2, b2, out);
}